// Round 1
// baseline (215.746 us; speedup 1.0000x reference)
//
#include <hip/hip_runtime.h>
#include <cstdint>
#include <cmath>

// Problem constants
#define NE 320000
#define NN 20000
#define NG 64

// ---------------------------------------------------------------------------
// Kernel 1: per-edge radial features for ONE layer.
// Computes bessel(r) (8), rad = silu(bessel @ w_r1 + b_r1) (64),
// then rw0[e][c] = sum_j rad[j] * w_r2_l[j][c] for c in 0..31 (the m=0 slice).
// Weights are read with wave-uniform indices -> scalar loads / L1 broadcast.
// ---------------------------------------------------------------------------
__global__ __launch_bounds__(256) void edge_kernel(
    const float* __restrict__ vectors,
    const float* __restrict__ w_r1,    // 8 x 64
    const float* __restrict__ b_r1,    // 64
    const float* __restrict__ w_r2_l,  // 64 x 96 (this layer)
    float* __restrict__ rw0,           // [E][32] out
    int E)
{
    int e = blockIdx.x * 256 + threadIdx.x;
    if (e >= E) return;

    float x = vectors[3 * e + 0];
    float y = vectors[3 * e + 1];
    float z = vectors[3 * e + 2];
    float r2 = x * x + y * y + z * z;
    float r = (r2 == 0.0f) ? 0.0f : sqrtf(r2);
    float rs = fmaxf(r, 1e-6f);
    float u = fminf(fmaxf(r * 0.2f, 0.0f), 1.0f);
    float env = (1.0f - u) * (1.0f - u) * (1.0f + 2.0f * u);
    float pref = 0.6324555320336759f * env / rs;   // sqrt(2/5) * env / rs
    float base = 0.6283185307179586f * rs;          // pi/5 * rs

    float b[8];
#pragma unroll
    for (int n = 0; n < 8; ++n) b[n] = pref * sinf((float)(n + 1) * base);

    float acc[32];
#pragma unroll
    for (int c = 0; c < 32; ++c) acc[c] = 0.0f;

    for (int j = 0; j < 64; ++j) {
        float pre = b_r1[j];
#pragma unroll
        for (int n = 0; n < 8; ++n) pre = fmaf(b[n], w_r1[n * 64 + j], pre);
        // silu
        float rj = pre / (1.0f + __expf(-pre));
        const float* w = w_r2_l + j * 96;  // m=0 slice: columns 0..31
#pragma unroll
        for (int c = 0; c < 32; ++c) acc[c] = fmaf(rj, w[c], acc[c]);
    }

    float4* dst = reinterpret_cast<float4*>(rw0 + (size_t)e * 32);
#pragma unroll
    for (int c = 0; c < 32; c += 4)
        dst[c >> 2] = make_float4(acc[c], acc[c + 1], acc[c + 2], acc[c + 3]);
}

// ---------------------------------------------------------------------------
// Kernel 2: h init = species_embed[node_species]
// ---------------------------------------------------------------------------
__global__ __launch_bounds__(256) void init_h_kernel(
    const int* __restrict__ spec, const float* __restrict__ emb,
    float* __restrict__ h, int N)
{
    int t = blockIdx.x * 256 + threadIdx.x;
    if (t >= N * 32) return;
    int n = t >> 5, c = t & 31;
    h[t] = emb[spec[n] * 32 + c];
}

// ---------------------------------------------------------------------------
// Kernel 3: message + segment_sum via atomics.
// thread = (edge, channel). val = rw0[e][c] * h[senders[e]][c]
// atomicAdd into agg[receivers[e]][c].
// ---------------------------------------------------------------------------
__global__ __launch_bounds__(256) void message_kernel(
    const float* __restrict__ rw0, const float* __restrict__ h,
    const int* __restrict__ senders, const int* __restrict__ receivers,
    float* __restrict__ agg, int E)
{
    int idx = blockIdx.x * 256 + threadIdx.x;
    if (idx >= E * 32) return;
    int e = idx >> 5, c = idx & 31;
    int s = senders[e];
    int rcv = receivers[e];
    float v = rw0[(size_t)e * 32 + c] * h[(size_t)s * 32 + c];
    atomicAdd(&agg[(size_t)rcv * 32 + c], v);
}

// ---------------------------------------------------------------------------
// Kernel 4: node update. h_out[n][d] = h[n][d]
//   + sum_c agg[n][c] * w_mix0[c][d]
//   + sum_c h[n][c]   * w_sc[spec[n]][c][d]
// ---------------------------------------------------------------------------
__global__ __launch_bounds__(256) void update_kernel(
    const float* __restrict__ agg, const float* __restrict__ h_in,
    const int* __restrict__ spec,
    const float* __restrict__ w_mix0,  // 32 x 32 (this layer, m=0)
    const float* __restrict__ w_sc_l,  // 64 x 32 x 32 (this layer)
    float* __restrict__ h_out, int N)
{
    int t = blockIdx.x * 256 + threadIdx.x;
    if (t >= N * 32) return;
    int n = t >> 5, d = t & 31;
    int s = spec[n];
    const float* wsc = w_sc_l + s * 1024 + d;
    const float* wmx = w_mix0 + d;
    const float* ag = agg + (size_t)n * 32;
    const float* hi = h_in + (size_t)n * 32;
    float acc = hi[d];
#pragma unroll
    for (int c = 0; c < 32; ++c) {
        acc = fmaf(ag[c], wmx[c * 32], acc);
        acc = fmaf(hi[c], wsc[c * 32], acc);
    }
    h_out[t] = acc;
}

// ---------------------------------------------------------------------------
// Kernel 5: readout (32->16), LayerNorm(16), MLP 16->64->1 (tanh-gelu),
// then segmented wave reduction over sorted graph_id, atomics into gsum/gcnt.
// ---------------------------------------------------------------------------
__global__ __launch_bounds__(256) void readout_kernel(
    const float* __restrict__ h, const int* __restrict__ gid_arr,
    const float* __restrict__ w_ro,   // 32 x 16
    const float* __restrict__ gamma, const float* __restrict__ beta,
    const float* __restrict__ w_h1,   // 16 x 64
    const float* __restrict__ b_h1,   // 64
    const float* __restrict__ w_h2,   // 64
    const float* __restrict__ b_h2,   // 1
    float* __restrict__ gsum, float* __restrict__ gcnt, int N)
{
    int t = blockIdx.x * 256 + threadIdx.x;
    int lane = threadIdx.x & 63;
    bool active = t < N;

    float val = 0.0f;
    int gid = -1;
    if (active) {
        gid = gid_arr[t];
        const float* hr = h + (size_t)t * 32;
        float ro[16];
#pragma unroll
        for (int o = 0; o < 16; ++o) ro[o] = 0.0f;
#pragma unroll
        for (int c = 0; c < 32; ++c) {
            float hv = hr[c];
#pragma unroll
            for (int o = 0; o < 16; ++o) ro[o] = fmaf(hv, w_ro[c * 16 + o], ro[o]);
        }
        float mu = 0.0f;
#pragma unroll
        for (int o = 0; o < 16; ++o) mu += ro[o];
        mu *= (1.0f / 16.0f);
        float var = 0.0f;
#pragma unroll
        for (int o = 0; o < 16; ++o) { float d = ro[o] - mu; var = fmaf(d, d, var); }
        var *= (1.0f / 16.0f);
        float inv = rsqrtf(var + 1e-6f);
        float nrm[16];
#pragma unroll
        for (int o = 0; o < 16; ++o) nrm[o] = (ro[o] - mu) * inv * gamma[o] + beta[o];

        float outv = b_h2[0];
        for (int j = 0; j < 64; ++j) {
            float a = b_h1[j];
#pragma unroll
            for (int o = 0; o < 16; ++o) a = fmaf(nrm[o], w_h1[o * 64 + j], a);
            float g = 0.5f * a * (1.0f + tanhf(0.7978845608028654f * (a + 0.044715f * a * a * a)));
            outv = fmaf(g, w_h2[j], outv);
        }
        val = outv;
    }
    float cval = active ? 1.0f : 0.0f;

    // segmented suffix reduction over sorted gid within the 64-lane wave
#pragma unroll
    for (int off = 1; off < 64; off <<= 1) {
        float v = __shfl_down(val, off);
        float cv = __shfl_down(cval, off);
        int g = __shfl_down(gid, off);
        if (lane + off < 64 && g == gid) { val += v; cval += cv; }
    }
    int gprev = __shfl_up(gid, 1);
    bool head = (lane == 0) || (gprev != gid);
    if (active && head) {
        atomicAdd(&gsum[gid], val);
        atomicAdd(&gcnt[gid], cval);
    }
}

// ---------------------------------------------------------------------------
// Kernel 6: finalize. out[g] = gsum/max(cnt,1)*scale + shift
// ---------------------------------------------------------------------------
__global__ void finalize_kernel(const float* __restrict__ gsum,
                                const float* __restrict__ gcnt,
                                const float* __restrict__ scale,
                                const float* __restrict__ shift,
                                float* __restrict__ out, int G)
{
    int g = blockIdx.x * blockDim.x + threadIdx.x;
    if (g < G) out[g] = gsum[g] / fmaxf(gcnt[g], 1.0f) * scale[0] + shift[0];
}

// ---------------------------------------------------------------------------
extern "C" void kernel_launch(void* const* d_in, const int* in_sizes, int n_in,
                              void* d_out, int out_size, void* d_ws, size_t ws_size,
                              hipStream_t stream)
{
    const float* vectors       = (const float*)d_in[0];
    const int*   node_species  = (const int*)d_in[1];
    const int*   senders       = (const int*)d_in[2];
    const int*   receivers     = (const int*)d_in[3];
    const int*   graph_id      = (const int*)d_in[4];
    const float* species_embed = (const float*)d_in[5];
    const float* w_r1          = (const float*)d_in[6];
    const float* b_r1          = (const float*)d_in[7];
    const float* w_r2          = (const float*)d_in[8];
    const float* w_mix         = (const float*)d_in[9];
    const float* w_sc          = (const float*)d_in[10];
    const float* w_ro          = (const float*)d_in[11];
    const float* ln_gamma      = (const float*)d_in[12];
    const float* ln_beta       = (const float*)d_in[13];
    const float* w_h1          = (const float*)d_in[14];
    const float* b_h1          = (const float*)d_in[15];
    const float* w_h2          = (const float*)d_in[16];
    const float* b_h2          = (const float*)d_in[17];
    const float* scale         = (const float*)d_in[18];
    const float* shift         = (const float*)d_in[19];
    float* out = (float*)d_out;

    const int E = NE, N = NN, G = NG;

    // workspace layout (floats):
    float* ws   = (float*)d_ws;
    float* rw0  = ws;                           // E*32
    float* hA   = rw0 + (size_t)E * 32;         // N*32
    float* hB   = hA + (size_t)N * 32;          // N*32
    float* agg  = hB + (size_t)N * 32;          // N*32
    float* gsum = agg + (size_t)N * 32;         // G
    float* gcnt = gsum + G;                     // G

    init_h_kernel<<<(N * 32 + 255) / 256, 256, 0, stream>>>(node_species, species_embed, hA, N);

    float* hin = hA;
    float* hout = hB;
    for (int li = 0; li < 2; ++li) {
        edge_kernel<<<(E + 255) / 256, 256, 0, stream>>>(
            vectors, w_r1, b_r1, w_r2 + (size_t)li * 64 * 96, rw0, E);
        hipMemsetAsync(agg, 0, (size_t)N * 32 * sizeof(float), stream);
        message_kernel<<<(E * 32 + 255) / 256, 256, 0, stream>>>(
            rw0, hin, senders, receivers, agg, E);
        update_kernel<<<(N * 32 + 255) / 256, 256, 0, stream>>>(
            agg, hin, node_species, w_mix + li * 3072, w_sc + li * 65536, hout, N);
        float* tmp = hin; hin = hout; hout = tmp;
    }

    hipMemsetAsync(gsum, 0, (size_t)2 * G * sizeof(float), stream);
    readout_kernel<<<(N + 255) / 256, 256, 0, stream>>>(
        hin, graph_id, w_ro, ln_gamma, ln_beta, w_h1, b_h1, w_h2, b_h2, gsum, gcnt, N);
    finalize_kernel<<<1, 64, 0, stream>>>(gsum, gcnt, scale, shift, out, G);
}